// Round 7
// baseline (2717.502 us; speedup 1.0000x reference)
//
#include <hip/hip_runtime.h>
#include <math.h>

// Problem constants
constexpr int BATCH = 2;
constexpr int C = 64;
constexpr int H = 256, W = 256;
constexpr int N = H * W;              // 65536 full-res pixels per (b,c)

// ---------------- workspace layout (in floats), peak ~145 MB ----------------
// Head-at-a-time scheduling: BIG_A holds K_h (then V first half), BIG_B holds
// QQ_h (then V second half). V = [BIG_A BIG_B] contiguous = [b][192][N].
constexpr size_t OFF_QN   = 0;                                   // ln(enc0) [b][64][N]
constexpr size_t OFF_Q1N  = OFF_QN  + (size_t)BATCH*C*N;         // ln(enc1) [b][64][128*128]
constexpr size_t OFF_Q2N  = OFF_Q1N + (size_t)BATCH*C*(N/4);     // ln(enc2) [b][64][64*64]
constexpr size_t OFF_DOTS = OFF_Q2N + (size_t)BATCH*C*(N/16);    // dots [b*2+h][96][96]
constexpr size_t OFF_QN2  = OFF_DOTS + (size_t)BATCH*2*96*96;    // q row norms^2 [bh][96]
constexpr size_t OFF_KN2  = OFF_QN2 + (size_t)BATCH*2*96;        // k row norms^2 [bh][96]
constexpr size_t OFF_ATT  = OFF_KN2 + (size_t)BATCH*2*96;        // attnT [s][b][h][96][32]
constexpr size_t OFF_WT   = OFF_ATT + (size_t)3*BATCH*2*96*32;   // transposed weights
constexpr size_t OFF_BIG  = OFF_WT + 45056;                      // 2 x 12,582,912 floats
constexpr size_t BIGHALF  = (size_t)BATCH*96*N;                  // 12,582,912
// NOTE: do NOT name this NZERO — glibc's <bits/xopen_lim.h> #defines NZERO.
constexpr int ACC_ZERO_N = (int)(BATCH*2*96*96 + BATCH*2*96 + BATCH*2*96); // dots+qn2+kn2

// ---------------- K0: zero the atomic accumulators ----------------
__global__ void zero_kernel(float* __restrict__ p, int n)
{
    int i = blockIdx.x * 256 + threadIdx.x;
    if (i < n) p[i] = 0.f;
}

// ---------------- K1: per-pixel channel LayerNorm ----------------
__global__ __launch_bounds__(256) void ln_kernel(
    const float* __restrict__ src, float* __restrict__ dst,
    const float* __restrict__ w, const float* __restrict__ bb, int HW)
{
    int gid = blockIdx.x * 256 + threadIdx.x;
    if (gid >= BATCH * HW) return;
    int b = gid / HW, p = gid % HW;
    const float* s = src + (size_t)b * C * HW + p;
    float x[C];
    float sum = 0.f;
#pragma unroll
    for (int c = 0; c < C; ++c) { x[c] = s[(size_t)c * HW]; sum += x[c]; }
    float mu = sum * (1.f / 64.f);
    float var = 0.f;
#pragma unroll
    for (int c = 0; c < C; ++c) { float d = x[c] - mu; var += d * d; }
    var *= (1.f / 64.f);
    float rs = 1.f / sqrtf(var + 1e-6f);
    float* o = dst + (size_t)b * C * HW + p;
#pragma unroll
    for (int c = 0; c < C; ++c) o[(size_t)c * HW] = w[c] * ((x[c] - mu) * rs) + bb[c];
}

// ---------------- prep: transpose the pointwise-conv weights ----------------
__global__ void wtrans_kernel(
    const float* __restrict__ po_w, const float* __restrict__ po1_w,
    const float* __restrict__ c4,  const float* __restrict__ c41, const float* __restrict__ c42,
    const float* __restrict__ c5,  const float* __restrict__ c51, const float* __restrict__ c52,
    float* __restrict__ wt)
{
    int m = blockIdx.x;
    const float* src; float* dst; int R, CC;
    if      (m == 0) { src = po_w;  dst = wt;              R = 64;  CC = 64; }
    else if (m == 1) { src = po1_w; dst = wt + 4096;       R = 64;  CC = 64; }
    else if (m == 2) { src = c4;    dst = wt + 8192;       R = 128; CC = 64; }
    else if (m == 3) { src = c41;   dst = wt + 16384;      R = 128; CC = 64; }
    else if (m == 4) { src = c42;   dst = wt + 24576;      R = 128; CC = 64; }
    else if (m == 5) { src = c5;    dst = wt + 32768;      R = 64;  CC = 64; }
    else if (m == 6) { src = c51;   dst = wt + 36864;      R = 64;  CC = 64; }
    else             { src = c52;   dst = wt + 40960;      R = 64;  CC = 64; }
    for (int idx = threadIdx.x; idx < R * CC; idx += 256)
        dst[(idx % CC) * R + (idx / CC)] = src[idx];
}

// ---------------- K2: fused conv1x1 + dwconv3 + norm^2 for one 32-ch chunk --------------
// MODE 0: kv chunk — output channel base kv_oc0 + z*32 of the 576-ch kv conv (ICN=192).
// MODE 1: q  chunk — scale s=z, rows rowb..rowb+31 of that scale's 64-ch q conv (ICN=64).
// Output row (z*32+oc) at outbase + (b*out_rows + z*32+oc)*N.
// normbase!=nullptr: atomicAdd y^2 into normbase[(b*2+h)*96 + z*32+oc].
template <int MODE>
__global__ __launch_bounds__(256, 3) void convdw_kernel(
    const float* __restrict__ qn, const float* __restrict__ q1n, const float* __restrict__ q2n,
    const float* __restrict__ kv_w, const float* __restrict__ kv_b,
    const float* __restrict__ kv_dww, const float* __restrict__ kv_dwb,
    const float* __restrict__ q_w,  const float* __restrict__ q_b,
    const float* __restrict__ q_dww,  const float* __restrict__ q_dwb,
    const float* __restrict__ q1_w, const float* __restrict__ q1_b,
    const float* __restrict__ q1_dww, const float* __restrict__ q1_dwb,
    const float* __restrict__ q2_w, const float* __restrict__ q2_b,
    const float* __restrict__ q2_dww, const float* __restrict__ q2_dwb,
    int kv_oc0, int rowb, int h, int out_rows,
    float* __restrict__ outbase, float* __restrict__ normbase)
{
    __shared__ float cbuf[32 * 324];   // conv1x1 output, 18x18 halo tile x 32 ch
    __shared__ float lnorm[32];
    const int t = threadIdx.x;
    const int tile = blockIdx.x;
    const int b = blockIdx.y;
    const int z = blockIdx.z;
    const int ty0 = (tile >> 4) * 16, tx0 = (tile & 15) * 16;

    const float *wrow, *cbias, *dww, *dwb;
    int ICN, ncb, qsrc_s = 0;
    if (MODE == 0) {
        int ocg = kv_oc0 + z * 32;
        wrow = kv_w + (size_t)ocg * 192; cbias = kv_b + ocg;
        dww = kv_dww + (size_t)ocg * 9;  dwb = kv_dwb + ocg;
        ICN = 192; ncb = 12;
    } else {
        qsrc_s = z;
        const float *qw, *qb, *qdw, *qdb;
        if (qsrc_s == 0)      { qw = q_w;  qb = q_b;  qdw = q_dww;  qdb = q_dwb; }
        else if (qsrc_s == 1) { qw = q1_w; qb = q1_b; qdw = q1_dww; qdb = q1_dwb; }
        else                  { qw = q2_w; qb = q2_b; qdw = q2_dww; qdb = q2_dwb; }
        wrow = qw + rowb * 64; cbias = qb + rowb;
        dww = qdw + rowb * 9;  dwb = qdb + rowb;
        ICN = 64; ncb = 4;
    }
    float* outp = outbase + ((size_t)b * out_rows + z * 32) * N;

    if (t < 32) lnorm[t] = 0.f;

    // conv1x1 over the 18x18 halo region (two passes of 256 threads)
    for (int pass = 0; pass < 2; ++pass) {
        int p = t + pass * 256;
        if (p < 324) {
            int hy = ty0 + p / 18 - 1, hx = tx0 + p % 18 - 1;
            bool in = (hy >= 0 && hy < H && hx >= 0 && hx < W);
            float acc[32];
#pragma unroll
            for (int o = 0; o < 32; ++o) acc[o] = in ? cbias[o] : 0.f;
            if (in) {
                for (int cb = 0; cb < ncb; ++cb) {
                    int sel = (MODE == 0) ? (cb >> 2) : qsrc_s;
                    int icb = (MODE == 0) ? ((cb & 3) * 16) : (cb * 16);
                    const float* src; int sh;
                    if (sel == 0)      { src = qn;  sh = 0; }
                    else if (sel == 1) { src = q1n; sh = 1; }
                    else               { src = q2n; sh = 2; }
                    int Wl = W >> sh;
                    int HWl = N >> (2 * sh);
                    const float* sp = src + ((size_t)b * 64 + icb) * HWl
                                      + (size_t)(hy >> sh) * Wl + (hx >> sh);
                    float xr[16];
#pragma unroll
                    for (int i = 0; i < 16; ++i) xr[i] = sp[(size_t)i * HWl];
                    const float* wp = wrow + cb * 16;
#pragma unroll
                    for (int o = 0; o < 32; ++o) {
#pragma unroll
                        for (int i = 0; i < 16; ++i)
                            acc[o] += wp[o * ICN + i] * xr[i];
                    }
                }
            }
#pragma unroll
            for (int o = 0; o < 32; ++o) cbuf[o * 324 + p] = acc[o];
        }
    }
    __syncthreads();

    // depthwise 3x3 (cross-correlation, zero 'SAME' padding) + write + norm^2
    {
        int py = t >> 4, px = t & 15;
        int hp = (py + 1) * 18 + (px + 1);
        int n = (ty0 + py) * W + tx0 + px;
        for (int oc = 0; oc < 32; ++oc) {
            float y = dwb[oc];
            const float* cb2 = cbuf + oc * 324 + hp;
            const float* dwp = dww + oc * 9;
#pragma unroll
            for (int ky = 0; ky < 3; ++ky)
#pragma unroll
                for (int kx = 0; kx < 3; ++kx)
                    y += cb2[(ky - 1) * 18 + (kx - 1)] * dwp[ky * 3 + kx];
            outp[(size_t)oc * N + n] = y;
            if (normbase) {
                float v2 = y * y;
#pragma unroll
                for (int off = 32; off >= 1; off >>= 1) v2 += __shfl_xor(v2, off);
                if ((t & 63) == 0) atomicAdd(&lnorm[oc], v2);
            }
        }
    }
    __syncthreads();
    if (normbase && t < 32)
        atomicAdd(&normbase[((size_t)b * 2 + h) * 96 + z * 32 + t], lnorm[t]);
}

// ---------------- K3: split-K dot reduction for ONE head (96 q-rows x 96 k-rows) --------
// qqh, kh: [b][96][N]. Writes dots[(b*2+h)*96*96 + row*96 + d] via atomics.
__global__ __launch_bounds__(256, 3) void attn_dots_kernel(
    const float* __restrict__ qqh, const float* __restrict__ kh,
    float* __restrict__ dots, int h)
{
    __shared__ float qlds[96 * 66];
    __shared__ float klds[96 * 66];
    const int t = threadIdx.x;
    const int seg = blockIdx.x;        // 128 K-segments of 512 pixels
    const int b = blockIdx.y;
    const int bh = b * 2 + h;
    const int k0 = seg * 512;
    const int tr = t >> 4, tc = t & 15;
    float acc[6][6];
#pragma unroll
    for (int i = 0; i < 6; ++i)
#pragma unroll
        for (int jj = 0; jj < 6; ++jj) acc[i][jj] = 0.f;

    for (int sub = 0; sub < 8; ++sub) {
        __syncthreads();
        int off = k0 + sub * 64;
        for (int it = 0; it < 24; ++it) {
            int idx = t + it * 256;
            int r = idx >> 6, px = idx & 63;
            qlds[r * 66 + px] = qqh[((size_t)b * 96 + r) * N + off + px];
            klds[r * 66 + px] = kh [((size_t)b * 96 + r) * N + off + px];
        }
        __syncthreads();
        for (int px = 0; px < 64; px += 2) {
            float2 qv[6], kvv[6];
#pragma unroll
            for (int i = 0; i < 6; ++i) qv[i]  = *(const float2*)&qlds[(tr * 6 + i) * 66 + px];
#pragma unroll
            for (int i = 0; i < 6; ++i) kvv[i] = *(const float2*)&klds[(tc * 6 + i) * 66 + px];
#pragma unroll
            for (int i = 0; i < 6; ++i)
#pragma unroll
                for (int jj = 0; jj < 6; ++jj)
                    acc[i][jj] += qv[i].x * kvv[jj].x + qv[i].y * kvv[jj].y;
        }
    }
    float* dp = dots + (size_t)bh * 96 * 96;
#pragma unroll
    for (int i = 0; i < 6; ++i)
#pragma unroll
        for (int jj = 0; jj < 6; ++jj)
            atomicAdd(&dp[(tr * 6 + i) * 96 + tc * 6 + jj], acc[i][jj]);
}

// ---------------- K4: normalize + temp scale + relu + softmax, write attnT ----------------
__global__ void attn_soft_kernel(
    const float* __restrict__ dots, const float* __restrict__ qn2, const float* __restrict__ kn2,
    const float* __restrict__ temp0, const float* __restrict__ temp1, const float* __restrict__ temp2,
    float* __restrict__ attnT)
{
    __shared__ float sv[96];
    __shared__ float red[2];
    const int bid = blockIdx.x;        // ((b*2+h)*3+s)*32+c
    const int c = bid & 31;
    const int s = (bid >> 5) % 3;
    const int bh = bid / 96;
    const int h = bh & 1, b = bh >> 1;
    const int t = threadIdx.x;
    const float* tp = (s == 0) ? temp0 : ((s == 1) ? temp1 : temp2);
    float val = 0.f, e = 0.f;
    if (t < 96) {
        float rq = 1.f / fmaxf(sqrtf(qn2[(size_t)bh * 96 + s * 32 + c]), 1e-12f);
        float rk = 1.f / fmaxf(sqrtf(kn2[(size_t)bh * 96 + t]), 1e-12f);
        val = dots[((size_t)bh * 96 + s * 32 + c) * 96 + t] * rq * rk * tp[h];
        val = fmaxf(val, 0.f);
        sv[t] = val;
    }
    __syncthreads();
    if (t == 0) { float m = sv[0]; for (int i = 1; i < 96; ++i) m = fmaxf(m, sv[i]); red[0] = m; }
    __syncthreads();
    if (t < 96) { e = expf(val - red[0]); sv[t] = e; }
    __syncthreads();
    if (t == 0) { float ssum = 0.f; for (int i = 0; i < 96; ++i) ssum += sv[i]; red[1] = ssum; }
    __syncthreads();
    if (t < 96)
        attnT[((((size_t)s * 2 + b) * 2 + h) * 96 + t) * 32 + c] = e / red[1];
}

// ---------------- K5: PV -> po -> residual -> LN -> conv4*gate -> conv5 -> out -------------
// NOTE: macro params must NOT be named x/y/z/w (float4 member capture).
#define FMA8(acc, wa, wb, v)                                                   \
    acc[0] += (wa).x * (v); acc[1] += (wa).y * (v);                            \
    acc[2] += (wa).z * (v); acc[3] += (wa).w * (v);                            \
    acc[4] += (wb).x * (v); acc[5] += (wb).y * (v);                            \
    acc[6] += (wb).z * (v); acc[7] += (wb).w * (v);

template <int ST>
__global__ __launch_bounds__(256, 3) void pv_ffn_kernel(
    const float* __restrict__ vsrc, const float* __restrict__ enc,
    const float* __restrict__ attnT,
    const float* __restrict__ powT, const float* __restrict__ pob,
    const float* __restrict__ n2w,  const float* __restrict__ n2b,
    const float* __restrict__ c4T,  const float* __restrict__ c4b,
    const float* __restrict__ c5T,  const float* __restrict__ c5b,
    const float* __restrict__ beta, const float* __restrict__ gamma,
    float* __restrict__ outp)
{
    constexpr int WL = W / ST;
    constexpr int HWL = WL * WL;
    __shared__ float vb[192 * 33];
    __shared__ float xb[32 * 65];
    __shared__ float yb[32 * 65];
    __shared__ float gb[32 * 65];
    __shared__ float mstat[2][32];

    const int t = threadIdx.x;
    const int bpb = HWL / 32;
    const int b = blockIdx.x / bpb;
    const int lp0 = (blockIdx.x % bpb) * 32;
    const int ly = lp0 / WL, lx0 = lp0 % WL;
    const size_t n0 = (size_t)(ly * ST) * W + (size_t)lx0 * ST;

    for (int it = 0; it < 24; ++it) {
        int idx = t + it * 256;
        int r = idx >> 5, px = idx & 31;
        vb[r * 33 + px] = vsrc[((size_t)b * 192 + r) * N + n0 + (size_t)px * ST];
    }
    __syncthreads();

    const int og = t >> 5;             // 8 output channels per group
    const int px = t & 31;
    const int head = og >> 2;
    const int cloc = (og & 3) * 8;
    const float* ab = attnT + (((size_t)b * 2 + head) * 96) * 32;

    {
        float acc[8] = {0, 0, 0, 0, 0, 0, 0, 0};
        for (int d = 0; d < 96; ++d) {
            float xv = vb[(head * 96 + d) * 33 + px];
            const float4* ap = reinterpret_cast<const float4*>(ab + d * 32 + cloc);
            float4 a0 = ap[0], a1 = ap[1];
            FMA8(acc, a0, a1, xv);
        }
#pragma unroll
        for (int i = 0; i < 8; ++i) xb[px * 65 + og * 8 + i] = acc[i];
    }
    __syncthreads();

    float yreg[8];
    {
        float acc[8] = {0, 0, 0, 0, 0, 0, 0, 0};
        for (int ch = 0; ch < 64; ++ch) {
            float xv = xb[px * 65 + ch];
            const float4* wp = reinterpret_cast<const float4*>(powT + ch * 64 + og * 8);
            float4 w0 = wp[0], w1 = wp[1];
            FMA8(acc, w0, w1, xv);
        }
#pragma unroll
        for (int i = 0; i < 8; ++i) {
            int o = og * 8 + i;
            float xo = acc[i] + pob[o];
            float ev = enc[((size_t)b * 64 + o) * HWL + lp0 + px];
            float yv = ev + xo * beta[o];
            yreg[i] = yv;
            yb[px * 65 + o] = yv;
        }
    }
    __syncthreads();

    if (t < 32) {
        float sum = 0.f;
        for (int ch = 0; ch < 64; ++ch) sum += yb[t * 65 + ch];
        float mu = sum * (1.f / 64.f);
        float var = 0.f;
        for (int ch = 0; ch < 64; ++ch) { float d = yb[t * 65 + ch] - mu; var += d * d; }
        mstat[0][t] = mu;
        mstat[1][t] = 1.f / sqrtf(var * (1.f / 64.f) + 1e-6f);
    }
    __syncthreads();

    {
        float mu = mstat[0][px], rs = mstat[1][px];
        float a1[8] = {0, 0, 0, 0, 0, 0, 0, 0};
        float a2[8] = {0, 0, 0, 0, 0, 0, 0, 0};
        for (int ch = 0; ch < 64; ++ch) {
            float tv = (yb[px * 65 + ch] - mu) * rs * n2w[ch] + n2b[ch];
            const float4* w1p = reinterpret_cast<const float4*>(c4T + ch * 128 + og * 8);
            const float4* w2p = reinterpret_cast<const float4*>(c4T + ch * 128 + 64 + og * 8);
            float4 wA = w1p[0], wB = w1p[1];
            float4 wC = w2p[0], wD = w2p[1];
            FMA8(a1, wA, wB, tv);
            FMA8(a2, wC, wD, tv);
        }
#pragma unroll
        for (int i = 0; i < 8; ++i) {
            int o = og * 8 + i;
            gb[px * 65 + o] = (a1[i] + c4b[o]) * (a2[i] + c4b[64 + o]);
        }
    }
    __syncthreads();

    {
        float acc[8] = {0, 0, 0, 0, 0, 0, 0, 0};
        for (int ch = 0; ch < 64; ++ch) {
            float gv = gb[px * 65 + ch];
            const float4* wp = reinterpret_cast<const float4*>(c5T + ch * 64 + og * 8);
            float4 w0 = wp[0], w1 = wp[1];
            FMA8(acc, w0, w1, gv);
        }
#pragma unroll
        for (int i = 0; i < 8; ++i) {
            int o = og * 8 + i;
            outp[((size_t)b * 64 + o) * HWL + lp0 + px] =
                yreg[i] + (acc[i] + c5b[o]) * gamma[o];
        }
    }
}

// ---------------- host launcher ----------------
extern "C" void kernel_launch(void* const* d_in, const int* in_sizes, int n_in,
                              void* d_out, int out_size, void* d_ws, size_t ws_size,
                              hipStream_t stream)
{
    const float* enc0 = (const float*)d_in[0];
    const float* enc1 = (const float*)d_in[1];
    const float* enc2 = (const float*)d_in[2];
    const float* kv_w = (const float*)d_in[3];
    const float* kv_b = (const float*)d_in[4];
    const float* kv_dww = (const float*)d_in[5];
    const float* kv_dwb = (const float*)d_in[6];
    const float* q_w  = (const float*)d_in[7];
    const float* q_b  = (const float*)d_in[8];
    const float* q_dww = (const float*)d_in[9];
    const float* q_dwb = (const float*)d_in[10];
    const float* q1_w = (const float*)d_in[11];
    const float* q1_b = (const float*)d_in[12];
    const float* q1_dww = (const float*)d_in[13];
    const float* q1_dwb = (const float*)d_in[14];
    const float* q2_w = (const float*)d_in[15];
    const float* q2_b = (const float*)d_in[16];
    const float* q2_dww = (const float*)d_in[17];
    const float* q2_dwb = (const float*)d_in[18];
    const float* po_w = (const float*)d_in[19];
    const float* po_b = (const float*)d_in[20];
    const float* po1_w = (const float*)d_in[21];
    const float* po1_b = (const float*)d_in[22];
    const float* temp0 = (const float*)d_in[23];
    const float* temp1 = (const float*)d_in[24];
    const float* temp2 = (const float*)d_in[25];
    const float* c4_w  = (const float*)d_in[26];
    const float* c4_b  = (const float*)d_in[27];
    const float* c5_w  = (const float*)d_in[28];
    const float* c5_b  = (const float*)d_in[29];
    const float* c41_w = (const float*)d_in[30];
    const float* c41_b = (const float*)d_in[31];
    const float* c51_w = (const float*)d_in[32];
    const float* c51_b = (const float*)d_in[33];
    const float* c42_w = (const float*)d_in[34];
    const float* c42_b = (const float*)d_in[35];
    const float* c52_w = (const float*)d_in[36];
    const float* c52_b = (const float*)d_in[37];
    const float* normq_w  = (const float*)d_in[38];
    const float* normq_b  = (const float*)d_in[39];
    const float* normq1_w = (const float*)d_in[40];
    const float* normq1_b = (const float*)d_in[41];
    const float* normq2_w = (const float*)d_in[42];
    const float* normq2_b = (const float*)d_in[43];
    const float* norm2_w  = (const float*)d_in[44];
    const float* norm2_b  = (const float*)d_in[45];
    const float* norm21_w = (const float*)d_in[46];
    const float* norm21_b = (const float*)d_in[47];
    const float* norm22_w = (const float*)d_in[48];
    const float* norm22_b = (const float*)d_in[49];
    const float* beta   = (const float*)d_in[50];
    const float* gamma  = (const float*)d_in[51];
    const float* beta1  = (const float*)d_in[52];
    const float* gamma1 = (const float*)d_in[53];
    const float* beta2  = (const float*)d_in[54];
    const float* gamma2 = (const float*)d_in[55];

    float* WS = (float*)d_ws;
    float* qn   = WS + OFF_QN;
    float* q1n  = WS + OFF_Q1N;
    float* q2n  = WS + OFF_Q2N;
    float* dots = WS + OFF_DOTS;
    float* qn2  = WS + OFF_QN2;
    float* kn2  = WS + OFF_KN2;
    float* attnT = WS + OFF_ATT;
    float* wt   = WS + OFF_WT;
    float* bigA = WS + OFF_BIG;            // K_h, then V rows 0..191 of b=0 + part of b=1
    float* bigB = WS + OFF_BIG + BIGHALF;  // QQ_h, then rest of V
    float* vbuf = bigA;                    // V = [b][192][N] spans bigA..bigB
    const float* poT  = wt;
    const float* po1T = wt + 4096;
    const float* c4T0 = wt + 8192;
    const float* c4T1 = wt + 16384;
    const float* c4T2 = wt + 24576;
    const float* c5T0 = wt + 32768;
    const float* c5T1 = wt + 36864;
    const float* c5T2 = wt + 40960;

    float* out0 = (float*)d_out;
    float* out1 = out0 + (size_t)BATCH * C * N;
    float* out2 = out1 + (size_t)BATCH * C * (N / 4);

    zero_kernel<<<(ACC_ZERO_N + 255) / 256, 256, 0, stream>>>(dots, ACC_ZERO_N);
    wtrans_kernel<<<8, 256, 0, stream>>>(po_w, po1_w, c4_w, c41_w, c42_w, c5_w, c51_w, c52_w, wt);

    ln_kernel<<<(BATCH * N + 255) / 256, 256, 0, stream>>>(enc0, qn, normq_w, normq_b, N);
    ln_kernel<<<(BATCH * (N / 4) + 255) / 256, 256, 0, stream>>>(enc1, q1n, normq1_w, normq1_b, N / 4);
    ln_kernel<<<(BATCH * (N / 16) + 255) / 256, 256, 0, stream>>>(enc2, q2n, normq2_w, normq2_b, N / 16);

#define CONV_ARGS qn, q1n, q2n, kv_w, kv_b, kv_dww, kv_dwb, \
    q_w, q_b, q_dww, q_dwb, q1_w, q1_b, q1_dww, q1_dwb, q2_w, q2_b, q2_dww, q2_dwb

    // head-at-a-time: K_h -> QQ_h -> dots_h  (bigA/bigB recycled per head, then as V)
    for (int h = 0; h < 2; ++h) {
        convdw_kernel<0><<<dim3(256, BATCH, 3), 256, 0, stream>>>(
            CONV_ARGS, /*kv_oc0=*/h * 96, /*rowb=*/0, h, /*out_rows=*/96, bigA, kn2);
        convdw_kernel<1><<<dim3(256, BATCH, 3), 256, 0, stream>>>(
            CONV_ARGS, /*kv_oc0=*/0, /*rowb=*/h * 32, h, /*out_rows=*/96, bigB, qn2);
        attn_dots_kernel<<<dim3(128, BATCH), 256, 0, stream>>>(bigB, bigA, dots, h);
    }
    // V (kv channels 192..383) into bigA..bigB as [b][192][N]
    convdw_kernel<0><<<dim3(256, BATCH, 6), 256, 0, stream>>>(
        CONV_ARGS, /*kv_oc0=*/192, /*rowb=*/0, 0, /*out_rows=*/192, vbuf, nullptr);

    attn_soft_kernel<<<384, 128, 0, stream>>>(dots, qn2, kn2, temp0, temp1, temp2, attnT);

    pv_ffn_kernel<1><<<BATCH * N / 32, 256, 0, stream>>>(
        vbuf, enc0, attnT, poT, po_b, norm2_w, norm2_b,
        c4T0, c4_b, c5T0, c5_b, beta, gamma, out0);
    pv_ffn_kernel<2><<<BATCH * (N / 4) / 32, 256, 0, stream>>>(
        vbuf, enc1, attnT + 12288, po1T, po1_b, norm21_w, norm21_b,
        c4T1, c41_b, c5T1, c51_b, beta1, gamma1, out1);
    pv_ffn_kernel<4><<<BATCH * (N / 16) / 32, 256, 0, stream>>>(
        vbuf, enc2, attnT + 24576, po1T, po1_b, norm22_w, norm22_b,
        c4T2, c42_b, c5T2, c52_b, beta2, gamma2, out2);
#undef CONV_ARGS
}

// Round 8
// 1897.875 us; speedup vs baseline: 1.4319x; 1.4319x over previous
//
#include <hip/hip_runtime.h>
#include <math.h>

// Problem constants
constexpr int BATCH = 2;
constexpr int C = 64;
constexpr int H = 256, W = 256;
constexpr int N = H * W;              // 65536 full-res pixels per (b,c)

// ---------------- workspace layout (in floats), peak ~145 MB ----------------
constexpr size_t OFF_QN   = 0;                                   // ln(enc0) [b][64][N]
constexpr size_t OFF_Q1N  = OFF_QN  + (size_t)BATCH*C*N;         // ln(enc1) [b][64][128*128]
constexpr size_t OFF_Q2N  = OFF_Q1N + (size_t)BATCH*C*(N/4);     // ln(enc2) [b][64][64*64]
constexpr size_t OFF_DOTS = OFF_Q2N + (size_t)BATCH*C*(N/16);    // dots [b*2+h][96][96]
constexpr size_t OFF_QN2  = OFF_DOTS + (size_t)BATCH*2*96*96;    // q row norms^2 [bh][96]
constexpr size_t OFF_KN2  = OFF_QN2 + (size_t)BATCH*2*96;        // k row norms^2 [bh][96]
constexpr size_t OFF_ATT  = OFF_KN2 + (size_t)BATCH*2*96;        // attnT [s][b][h][96][32]
constexpr size_t OFF_WT   = OFF_ATT + (size_t)3*BATCH*2*96*32;   // transposed weights
constexpr size_t OFF_BIG  = OFF_WT + 45056;                      // 2 x 12,582,912 floats
constexpr size_t BIGHALF  = (size_t)BATCH*96*N;                  // 12,582,912
// NOTE: do NOT name this NZERO — glibc's <bits/xopen_lim.h> #defines NZERO.
constexpr int ACC_ZERO_N = (int)(BATCH*2*96*96 + BATCH*2*96 + BATCH*2*96); // dots+qn2+kn2

// ---------------- K0: zero the atomic accumulators ----------------
__global__ void zero_kernel(float* __restrict__ p, int n)
{
    int i = blockIdx.x * 256 + threadIdx.x;
    if (i < n) p[i] = 0.f;
}

// ---------------- K1: per-pixel channel LayerNorm ----------------
__global__ __launch_bounds__(256) void ln_kernel(
    const float* __restrict__ src, float* __restrict__ dst,
    const float* __restrict__ w, const float* __restrict__ bb, int HW)
{
    int gid = blockIdx.x * 256 + threadIdx.x;
    if (gid >= BATCH * HW) return;
    int b = gid / HW, p = gid % HW;
    const float* s = src + (size_t)b * C * HW + p;
    float x[C];
    float sum = 0.f;
#pragma unroll
    for (int c = 0; c < C; ++c) { x[c] = s[(size_t)c * HW]; sum += x[c]; }
    float mu = sum * (1.f / 64.f);
    float var = 0.f;
#pragma unroll
    for (int c = 0; c < C; ++c) { float d = x[c] - mu; var += d * d; }
    var *= (1.f / 64.f);
    float rs = 1.f / sqrtf(var + 1e-6f);
    float* o = dst + (size_t)b * C * HW + p;
#pragma unroll
    for (int c = 0; c < C; ++c) o[(size_t)c * HW] = w[c] * ((x[c] - mu) * rs) + bb[c];
}

// ---------------- prep: transpose the pointwise-conv weights ----------------
__global__ void wtrans_kernel(
    const float* __restrict__ po_w, const float* __restrict__ po1_w,
    const float* __restrict__ c4,  const float* __restrict__ c41, const float* __restrict__ c42,
    const float* __restrict__ c5,  const float* __restrict__ c51, const float* __restrict__ c52,
    float* __restrict__ wt)
{
    int m = blockIdx.x;
    const float* src; float* dst; int R, CC;
    if      (m == 0) { src = po_w;  dst = wt;              R = 64;  CC = 64; }
    else if (m == 1) { src = po1_w; dst = wt + 4096;       R = 64;  CC = 64; }
    else if (m == 2) { src = c4;    dst = wt + 8192;       R = 128; CC = 64; }
    else if (m == 3) { src = c41;   dst = wt + 16384;      R = 128; CC = 64; }
    else if (m == 4) { src = c42;   dst = wt + 24576;      R = 128; CC = 64; }
    else if (m == 5) { src = c5;    dst = wt + 32768;      R = 64;  CC = 64; }
    else if (m == 6) { src = c51;   dst = wt + 36864;      R = 64;  CC = 64; }
    else             { src = c52;   dst = wt + 40960;      R = 64;  CC = 64; }
    for (int idx = threadIdx.x; idx < R * CC; idx += 256)
        dst[(idx % CC) * R + (idx / CC)] = src[idx];
}

// ---------------- K2: fused conv1x1 + dwconv3 + norm^2 for one 16-ch chunk --------------
// 1-D grid, XCD-swizzled: id -> (xcd = id&7, z = (id>>3)%Z, ti = xcd + 8*((id>>3)/Z)).
// Same-tile z-chunks land consecutively on ONE XCD -> input tile read once from HBM,
// remaining chunks hit that XCD's L2. (z-chunk = 16 output channels; LDS 20.8KB -> 7 blk/CU.)
// MODE 0: kv chunk — output channels kv_oc0 + z*16 .. +15 of the 576-ch kv conv (ICN=192).
// MODE 1: q  chunk — scale s=z/2, half part=z%2 -> weight rows h*32+part*16, out row s*32+part*16.
template <int MODE>
__global__ __launch_bounds__(256, 7) void convdw_kernel(
    const float* __restrict__ qn, const float* __restrict__ q1n, const float* __restrict__ q2n,
    const float* __restrict__ kv_w, const float* __restrict__ kv_b,
    const float* __restrict__ kv_dww, const float* __restrict__ kv_dwb,
    const float* __restrict__ q_w,  const float* __restrict__ q_b,
    const float* __restrict__ q_dww,  const float* __restrict__ q_dwb,
    const float* __restrict__ q1_w, const float* __restrict__ q1_b,
    const float* __restrict__ q1_dww, const float* __restrict__ q1_dwb,
    const float* __restrict__ q2_w, const float* __restrict__ q2_b,
    const float* __restrict__ q2_dww, const float* __restrict__ q2_dwb,
    int kv_oc0, int h, int out_rows, int Z,
    float* __restrict__ outbase, float* __restrict__ normbase)
{
    __shared__ float cbuf[16 * 324];   // conv1x1 output, 18x18 halo tile x 16 ch
    __shared__ float lnorm[16];
    const int t = threadIdx.x;
    // XCD-aware swizzle: z innermost within an XCD's block sequence.
    const int id  = blockIdx.x;
    const int xcd = id & 7;
    const int wq  = id >> 3;
    const int z   = wq % Z;
    const int g   = wq / Z;            // 0..63
    const int ti  = xcd + 8 * g;       // 0..511 tile-instance (512 % 8 == 0 keeps XCD fixed)
    const int tile = ti & 255;
    const int b    = ti >> 8;
    const int ty0 = (tile >> 4) * 16, tx0 = (tile & 15) * 16;

    const float *wrow, *cbias, *dww, *dwb;
    int ICN, ncb, qsrc_s = 0, out_row, norm_idx;
    if (MODE == 0) {
        int ocg = kv_oc0 + z * 16;
        wrow = kv_w + (size_t)ocg * 192; cbias = kv_b + ocg;
        dww = kv_dww + (size_t)ocg * 9;  dwb = kv_dwb + ocg;
        ICN = 192; ncb = 12;
        out_row = z * 16;
        norm_idx = z * 16;             // k channel within head (0..95)
    } else {
        qsrc_s = z >> 1;
        int part = z & 1;
        const float *qw, *qb, *qdw, *qdb;
        if (qsrc_s == 0)      { qw = q_w;  qb = q_b;  qdw = q_dww;  qdb = q_dwb; }
        else if (qsrc_s == 1) { qw = q1_w; qb = q1_b; qdw = q1_dww; qdb = q1_dwb; }
        else                  { qw = q2_w; qb = q2_b; qdw = q2_dww; qdb = q2_dwb; }
        int wr = h * 32 + part * 16;
        wrow = qw + wr * 64; cbias = qb + wr;
        dww = qdw + wr * 9;  dwb = qdb + wr;
        ICN = 64; ncb = 4;
        out_row = qsrc_s * 32 + part * 16;
        norm_idx = qsrc_s * 32 + part * 16;
    }
    float* outp = outbase + ((size_t)b * out_rows + out_row) * N;

    if (t < 16) lnorm[t] = 0.f;

    // conv1x1 over the 18x18 halo region (two passes of 256 threads)
    for (int pass = 0; pass < 2; ++pass) {
        int p = t + pass * 256;
        if (p < 324) {
            int hy = ty0 + p / 18 - 1, hx = tx0 + p % 18 - 1;
            bool in = (hy >= 0 && hy < H && hx < W && hx >= 0);
            float acc[16];
#pragma unroll
            for (int o = 0; o < 16; ++o) acc[o] = in ? cbias[o] : 0.f;
            if (in) {
                for (int cb = 0; cb < ncb; ++cb) {
                    int sel = (MODE == 0) ? (cb >> 2) : qsrc_s;
                    int icb = (MODE == 0) ? ((cb & 3) * 16) : (cb * 16);
                    const float* src; int sh;
                    if (sel == 0)      { src = qn;  sh = 0; }
                    else if (sel == 1) { src = q1n; sh = 1; }
                    else               { src = q2n; sh = 2; }
                    int Wl = W >> sh;
                    int HWl = N >> (2 * sh);
                    const float* sp = src + ((size_t)b * 64 + icb) * HWl
                                      + (size_t)(hy >> sh) * Wl + (hx >> sh);
                    float xr[16];
#pragma unroll
                    for (int i = 0; i < 16; ++i) xr[i] = sp[(size_t)i * HWl];
                    const float* wp = wrow + cb * 16;
#pragma unroll
                    for (int o = 0; o < 16; ++o) {
#pragma unroll
                        for (int i = 0; i < 16; ++i)
                            acc[o] += wp[o * ICN + i] * xr[i];
                    }
                }
            }
#pragma unroll
            for (int o = 0; o < 16; ++o) cbuf[o * 324 + p] = acc[o];
        }
    }
    __syncthreads();

    // depthwise 3x3 (cross-correlation, zero 'SAME' padding) + write + norm^2
    {
        int py = t >> 4, px = t & 15;
        int hp = (py + 1) * 18 + (px + 1);
        int n = (ty0 + py) * W + tx0 + px;
        for (int oc = 0; oc < 16; ++oc) {
            float y = dwb[oc];
            const float* cb2 = cbuf + oc * 324 + hp;
            const float* dwp = dww + oc * 9;
#pragma unroll
            for (int ky = 0; ky < 3; ++ky)
#pragma unroll
                for (int kx = 0; kx < 3; ++kx)
                    y += cb2[(ky - 1) * 18 + (kx - 1)] * dwp[ky * 3 + kx];
            outp[(size_t)oc * N + n] = y;
            if (normbase) {
                float v2 = y * y;
#pragma unroll
                for (int off = 32; off >= 1; off >>= 1) v2 += __shfl_xor(v2, off);
                if ((t & 63) == 0) atomicAdd(&lnorm[oc], v2);
            }
        }
    }
    __syncthreads();
    if (normbase && t < 16)
        atomicAdd(&normbase[((size_t)b * 2 + h) * 96 + norm_idx + t], lnorm[t]);
}

// ---------------- K3: split-K dot reduction for ONE head (96 q-rows x 96 k-rows) --------
__global__ __launch_bounds__(256, 3) void attn_dots_kernel(
    const float* __restrict__ qqh, const float* __restrict__ kh,
    float* __restrict__ dots, int h)
{
    __shared__ float qlds[96 * 66];
    __shared__ float klds[96 * 66];
    const int t = threadIdx.x;
    const int seg = blockIdx.x;        // 128 K-segments of 512 pixels
    const int b = blockIdx.y;
    const int bh = b * 2 + h;
    const int k0 = seg * 512;
    const int tr = t >> 4, tc = t & 15;
    float acc[6][6];
#pragma unroll
    for (int i = 0; i < 6; ++i)
#pragma unroll
        for (int jj = 0; jj < 6; ++jj) acc[i][jj] = 0.f;

    for (int sub = 0; sub < 8; ++sub) {
        __syncthreads();
        int off = k0 + sub * 64;
        for (int it = 0; it < 24; ++it) {
            int idx = t + it * 256;
            int r = idx >> 6, px = idx & 63;
            qlds[r * 66 + px] = qqh[((size_t)b * 96 + r) * N + off + px];
            klds[r * 66 + px] = kh [((size_t)b * 96 + r) * N + off + px];
        }
        __syncthreads();
        for (int px = 0; px < 64; px += 2) {
            float2 qv[6], kvv[6];
#pragma unroll
            for (int i = 0; i < 6; ++i) qv[i]  = *(const float2*)&qlds[(tr * 6 + i) * 66 + px];
#pragma unroll
            for (int i = 0; i < 6; ++i) kvv[i] = *(const float2*)&klds[(tc * 6 + i) * 66 + px];
#pragma unroll
            for (int i = 0; i < 6; ++i)
#pragma unroll
                for (int jj = 0; jj < 6; ++jj)
                    acc[i][jj] += qv[i].x * kvv[jj].x + qv[i].y * kvv[jj].y;
        }
    }
    float* dp = dots + (size_t)bh * 96 * 96;
#pragma unroll
    for (int i = 0; i < 6; ++i)
#pragma unroll
        for (int jj = 0; jj < 6; ++jj)
            atomicAdd(&dp[(tr * 6 + i) * 96 + tc * 6 + jj], acc[i][jj]);
}

// ---------------- K4: normalize + temp scale + relu + softmax, write attnT ----------------
__global__ void attn_soft_kernel(
    const float* __restrict__ dots, const float* __restrict__ qn2, const float* __restrict__ kn2,
    const float* __restrict__ temp0, const float* __restrict__ temp1, const float* __restrict__ temp2,
    float* __restrict__ attnT)
{
    __shared__ float sv[96];
    __shared__ float red[2];
    const int bid = blockIdx.x;        // ((b*2+h)*3+s)*32+c
    const int c = bid & 31;
    const int s = (bid >> 5) % 3;
    const int bh = bid / 96;
    const int h = bh & 1, b = bh >> 1;
    const int t = threadIdx.x;
    const float* tp = (s == 0) ? temp0 : ((s == 1) ? temp1 : temp2);
    float val = 0.f, e = 0.f;
    if (t < 96) {
        float rq = 1.f / fmaxf(sqrtf(qn2[(size_t)bh * 96 + s * 32 + c]), 1e-12f);
        float rk = 1.f / fmaxf(sqrtf(kn2[(size_t)bh * 96 + t]), 1e-12f);
        val = dots[((size_t)bh * 96 + s * 32 + c) * 96 + t] * rq * rk * tp[h];
        val = fmaxf(val, 0.f);
        sv[t] = val;
    }
    __syncthreads();
    if (t == 0) { float m = sv[0]; for (int i = 1; i < 96; ++i) m = fmaxf(m, sv[i]); red[0] = m; }
    __syncthreads();
    if (t < 96) { e = expf(val - red[0]); sv[t] = e; }
    __syncthreads();
    if (t == 0) { float ssum = 0.f; for (int i = 0; i < 96; ++i) ssum += sv[i]; red[1] = ssum; }
    __syncthreads();
    if (t < 96)
        attnT[((((size_t)s * 2 + b) * 2 + h) * 96 + t) * 32 + c] = e / red[1];
}

// ---------------- K5: PV -> po -> residual -> LN -> conv4*gate -> conv5 -> out -------------
// NOTE: macro params must NOT be named x/y/z/w (float4 member capture).
#define FMA8(acc, wa, wb, v)                                                   \
    acc[0] += (wa).x * (v); acc[1] += (wa).y * (v);                            \
    acc[2] += (wa).z * (v); acc[3] += (wa).w * (v);                            \
    acc[4] += (wb).x * (v); acc[5] += (wb).y * (v);                            \
    acc[6] += (wb).z * (v); acc[7] += (wb).w * (v);

template <int ST>
__global__ __launch_bounds__(256, 3) void pv_ffn_kernel(
    const float* __restrict__ vsrc, const float* __restrict__ enc,
    const float* __restrict__ attnT,
    const float* __restrict__ powT, const float* __restrict__ pob,
    const float* __restrict__ n2w,  const float* __restrict__ n2b,
    const float* __restrict__ c4T,  const float* __restrict__ c4b,
    const float* __restrict__ c5T,  const float* __restrict__ c5b,
    const float* __restrict__ beta, const float* __restrict__ gamma,
    float* __restrict__ outp)
{
    constexpr int WL = W / ST;
    constexpr int HWL = WL * WL;
    __shared__ float vb[192 * 33];
    __shared__ float xb[32 * 65];
    __shared__ float yb[32 * 65];
    __shared__ float gb[32 * 65];
    __shared__ float mstat[2][32];

    const int t = threadIdx.x;
    const int bpb = HWL / 32;
    const int b = blockIdx.x / bpb;
    const int lp0 = (blockIdx.x % bpb) * 32;
    const int ly = lp0 / WL, lx0 = lp0 % WL;
    const size_t n0 = (size_t)(ly * ST) * W + (size_t)lx0 * ST;

    for (int it = 0; it < 24; ++it) {
        int idx = t + it * 256;
        int r = idx >> 5, px = idx & 31;
        vb[r * 33 + px] = vsrc[((size_t)b * 192 + r) * N + n0 + (size_t)px * ST];
    }
    __syncthreads();

    const int og = t >> 5;             // 8 output channels per group
    const int px = t & 31;
    const int head = og >> 2;
    const int cloc = (og & 3) * 8;
    const float* ab = attnT + (((size_t)b * 2 + head) * 96) * 32;

    {
        float acc[8] = {0, 0, 0, 0, 0, 0, 0, 0};
        for (int d = 0; d < 96; ++d) {
            float xv = vb[(head * 96 + d) * 33 + px];
            const float4* ap = reinterpret_cast<const float4*>(ab + d * 32 + cloc);
            float4 a0 = ap[0], a1 = ap[1];
            FMA8(acc, a0, a1, xv);
        }
#pragma unroll
        for (int i = 0; i < 8; ++i) xb[px * 65 + og * 8 + i] = acc[i];
    }
    __syncthreads();

    float yreg[8];
    {
        float acc[8] = {0, 0, 0, 0, 0, 0, 0, 0};
        for (int ch = 0; ch < 64; ++ch) {
            float xv = xb[px * 65 + ch];
            const float4* wp = reinterpret_cast<const float4*>(powT + ch * 64 + og * 8);
            float4 w0 = wp[0], w1 = wp[1];
            FMA8(acc, w0, w1, xv);
        }
#pragma unroll
        for (int i = 0; i < 8; ++i) {
            int o = og * 8 + i;
            float xo = acc[i] + pob[o];
            float ev = enc[((size_t)b * 64 + o) * HWL + lp0 + px];
            float yv = ev + xo * beta[o];
            yreg[i] = yv;
            yb[px * 65 + o] = yv;
        }
    }
    __syncthreads();

    if (t < 32) {
        float sum = 0.f;
        for (int ch = 0; ch < 64; ++ch) sum += yb[t * 65 + ch];
        float mu = sum * (1.f / 64.f);
        float var = 0.f;
        for (int ch = 0; ch < 64; ++ch) { float d = yb[t * 65 + ch] - mu; var += d * d; }
        mstat[0][t] = mu;
        mstat[1][t] = 1.f / sqrtf(var * (1.f / 64.f) + 1e-6f);
    }
    __syncthreads();

    {
        float mu = mstat[0][px], rs = mstat[1][px];
        float a1[8] = {0, 0, 0, 0, 0, 0, 0, 0};
        float a2[8] = {0, 0, 0, 0, 0, 0, 0, 0};
        for (int ch = 0; ch < 64; ++ch) {
            float tv = (yb[px * 65 + ch] - mu) * rs * n2w[ch] + n2b[ch];
            const float4* w1p = reinterpret_cast<const float4*>(c4T + ch * 128 + og * 8);
            const float4* w2p = reinterpret_cast<const float4*>(c4T + ch * 128 + 64 + og * 8);
            float4 wA = w1p[0], wB = w1p[1];
            float4 wC = w2p[0], wD = w2p[1];
            FMA8(a1, wA, wB, tv);
            FMA8(a2, wC, wD, tv);
        }
#pragma unroll
        for (int i = 0; i < 8; ++i) {
            int o = og * 8 + i;
            gb[px * 65 + o] = (a1[i] + c4b[o]) * (a2[i] + c4b[64 + o]);
        }
    }
    __syncthreads();

    {
        float acc[8] = {0, 0, 0, 0, 0, 0, 0, 0};
        for (int ch = 0; ch < 64; ++ch) {
            float gv = gb[px * 65 + ch];
            const float4* wp = reinterpret_cast<const float4*>(c5T + ch * 64 + og * 8);
            float4 w0 = wp[0], w1 = wp[1];
            FMA8(acc, w0, w1, gv);
        }
#pragma unroll
        for (int i = 0; i < 8; ++i) {
            int o = og * 8 + i;
            outp[((size_t)b * 64 + o) * HWL + lp0 + px] =
                yreg[i] + (acc[i] + c5b[o]) * gamma[o];
        }
    }
}

// ---------------- host launcher ----------------
extern "C" void kernel_launch(void* const* d_in, const int* in_sizes, int n_in,
                              void* d_out, int out_size, void* d_ws, size_t ws_size,
                              hipStream_t stream)
{
    const float* enc0 = (const float*)d_in[0];
    const float* enc1 = (const float*)d_in[1];
    const float* enc2 = (const float*)d_in[2];
    const float* kv_w = (const float*)d_in[3];
    const float* kv_b = (const float*)d_in[4];
    const float* kv_dww = (const float*)d_in[5];
    const float* kv_dwb = (const float*)d_in[6];
    const float* q_w  = (const float*)d_in[7];
    const float* q_b  = (const float*)d_in[8];
    const float* q_dww = (const float*)d_in[9];
    const float* q_dwb = (const float*)d_in[10];
    const float* q1_w = (const float*)d_in[11];
    const float* q1_b = (const float*)d_in[12];
    const float* q1_dww = (const float*)d_in[13];
    const float* q1_dwb = (const float*)d_in[14];
    const float* q2_w = (const float*)d_in[15];
    const float* q2_b = (const float*)d_in[16];
    const float* q2_dww = (const float*)d_in[17];
    const float* q2_dwb = (const float*)d_in[18];
    const float* po_w = (const float*)d_in[19];
    const float* po_b = (const float*)d_in[20];
    const float* po1_w = (const float*)d_in[21];
    const float* po1_b = (const float*)d_in[22];
    const float* temp0 = (const float*)d_in[23];
    const float* temp1 = (const float*)d_in[24];
    const float* temp2 = (const float*)d_in[25];
    const float* c4_w  = (const float*)d_in[26];
    const float* c4_b  = (const float*)d_in[27];
    const float* c5_w  = (const float*)d_in[28];
    const float* c5_b  = (const float*)d_in[29];
    const float* c41_w = (const float*)d_in[30];
    const float* c41_b = (const float*)d_in[31];
    const float* c51_w = (const float*)d_in[32];
    const float* c51_b = (const float*)d_in[33];
    const float* c42_w = (const float*)d_in[34];
    const float* c42_b = (const float*)d_in[35];
    const float* c52_w = (const float*)d_in[36];
    const float* c52_b = (const float*)d_in[37];
    const float* normq_w  = (const float*)d_in[38];
    const float* normq_b  = (const float*)d_in[39];
    const float* normq1_w = (const float*)d_in[40];
    const float* normq1_b = (const float*)d_in[41];
    const float* normq2_w = (const float*)d_in[42];
    const float* normq2_b = (const float*)d_in[43];
    const float* norm2_w  = (const float*)d_in[44];
    const float* norm2_b  = (const float*)d_in[45];
    const float* norm21_w = (const float*)d_in[46];
    const float* norm21_b = (const float*)d_in[47];
    const float* norm22_w = (const float*)d_in[48];
    const float* norm22_b = (const float*)d_in[49];
    const float* beta   = (const float*)d_in[50];
    const float* gamma  = (const float*)d_in[51];
    const float* beta1  = (const float*)d_in[52];
    const float* gamma1 = (const float*)d_in[53];
    const float* beta2  = (const float*)d_in[54];
    const float* gamma2 = (const float*)d_in[55];

    float* WS = (float*)d_ws;
    float* qn   = WS + OFF_QN;
    float* q1n  = WS + OFF_Q1N;
    float* q2n  = WS + OFF_Q2N;
    float* dots = WS + OFF_DOTS;
    float* qn2  = WS + OFF_QN2;
    float* kn2  = WS + OFF_KN2;
    float* attnT = WS + OFF_ATT;
    float* wt   = WS + OFF_WT;
    float* bigA = WS + OFF_BIG;            // K_h, then V rows (first half)
    float* bigB = WS + OFF_BIG + BIGHALF;  // QQ_h, then rest of V
    float* vbuf = bigA;                    // V = [b][192][N] spans bigA..bigB
    const float* poT  = wt;
    const float* po1T = wt + 4096;
    const float* c4T0 = wt + 8192;
    const float* c4T1 = wt + 16384;
    const float* c4T2 = wt + 24576;
    const float* c5T0 = wt + 32768;
    const float* c5T1 = wt + 36864;
    const float* c5T2 = wt + 40960;

    float* out0 = (float*)d_out;
    float* out1 = out0 + (size_t)BATCH * C * N;
    float* out2 = out1 + (size_t)BATCH * C * (N / 4);

    zero_kernel<<<(ACC_ZERO_N + 255) / 256, 256, 0, stream>>>(dots, ACC_ZERO_N);
    wtrans_kernel<<<8, 256, 0, stream>>>(po_w, po1_w, c4_w, c41_w, c42_w, c5_w, c51_w, c52_w, wt);

    ln_kernel<<<(BATCH * N + 255) / 256, 256, 0, stream>>>(enc0, qn, normq_w, normq_b, N);
    ln_kernel<<<(BATCH * (N / 4) + 255) / 256, 256, 0, stream>>>(enc1, q1n, normq1_w, normq1_b, N / 4);
    ln_kernel<<<(BATCH * (N / 16) + 255) / 256, 256, 0, stream>>>(enc2, q2n, normq2_w, normq2_b, N / 16);

#define CONV_ARGS qn, q1n, q2n, kv_w, kv_b, kv_dww, kv_dwb, \
    q_w, q_b, q_dww, q_dwb, q1_w, q1_b, q1_dww, q1_dwb, q2_w, q2_b, q2_dww, q2_dwb

    // head-at-a-time: K_h -> QQ_h -> dots_h  (bigA/bigB recycled per head, then as V)
    for (int h = 0; h < 2; ++h) {
        convdw_kernel<0><<<512 * 6, 256, 0, stream>>>(
            CONV_ARGS, /*kv_oc0=*/h * 96, h, /*out_rows=*/96, /*Z=*/6, bigA, kn2);
        convdw_kernel<1><<<512 * 6, 256, 0, stream>>>(
            CONV_ARGS, /*kv_oc0=*/0, h, /*out_rows=*/96, /*Z=*/6, bigB, qn2);
        attn_dots_kernel<<<dim3(128, BATCH), 256, 0, stream>>>(bigB, bigA, dots, h);
    }
    // V (kv channels 192..383) into bigA..bigB as [b][192][N]
    convdw_kernel<0><<<512 * 12, 256, 0, stream>>>(
        CONV_ARGS, /*kv_oc0=*/192, /*h=*/0, /*out_rows=*/192, /*Z=*/12, vbuf, nullptr);

    attn_soft_kernel<<<384, 128, 0, stream>>>(dots, qn2, kn2, temp0, temp1, temp2, attnT);

    pv_ffn_kernel<1><<<BATCH * N / 32, 256, 0, stream>>>(
        vbuf, enc0, attnT, poT, po_b, norm2_w, norm2_b,
        c4T0, c4_b, c5T0, c5_b, beta, gamma, out0);
    pv_ffn_kernel<2><<<BATCH * (N / 4) / 32, 256, 0, stream>>>(
        vbuf, enc1, attnT + 12288, po1T, po1_b, norm21_w, norm21_b,
        c4T1, c41_b, c5T1, c51_b, beta1, gamma1, out1);
    pv_ffn_kernel<4><<<BATCH * (N / 16) / 32, 256, 0, stream>>>(
        vbuf, enc2, attnT + 24576, po1T, po1_b, norm22_w, norm22_b,
        c4T2, c42_b, c5T2, c52_b, beta2, gamma2, out2);
#undef CONV_ARGS
}